// Round 11
// baseline (858.411 us; speedup 1.0000x reference)
//
#include <hip/hip_runtime.h>

#define KNB 8
#define OCC_R 0.25f
#define BIGF 1e30f
#define NB 512
#define XLO -6.0f
#define XBW (12.0f / NB)
#define XINVBW (NB / 12.0f)

__device__ __forceinline__ float med3f(float a, float b, float c) {
#if defined(__has_builtin) && __has_builtin(__builtin_amdgcn_fmed3f)
    return __builtin_amdgcn_fmed3f(a, b, c);   // single v_med3_f32
#else
    return fmaxf(fminf(a, b), fminf(fmaxf(a, b), c));
#endif
}

// Unconditional parallel insert of x into sorted-ascending b0..b7 (drops old b7).
#define INS8(val) { float x = (val);          \
    b7 = med3f(b6, b7, x);                    \
    b6 = med3f(b5, b6, x);                    \
    b5 = med3f(b4, b5, x);                    \
    b4 = med3f(b3, b4, x);                    \
    b3 = med3f(b2, b3, x);                    \
    b2 = med3f(b1, b2, x);                    \
    b1 = med3f(b0, b1, x);                    \
    b0 = fminf(b0, x); }

#define PROC(c) { float d2 = q2 + (c).w;      \
    d2 = fmaf((c).x, qx, d2);                 \
    d2 = fmaf((c).y, qy, d2);                 \
    d2 = fmaf((c).z, qz, d2);                 \
    INS8(d2); }

// scan all targets in bucket bb (4-batched loads so vmcnt pipelines)
#define SCANB(bb) { int j = start_t[bb], e = start_t[(bb) + 1];          \
    for (; j + 3 < e; j += 4) {                                          \
        float4 c0 = ts[j], c1 = ts[j + 1], c2 = ts[j + 2], c3 = ts[j + 3]; \
        PROC(c0); PROC(c1); PROC(c2); PROC(c3);                          \
    }                                                                    \
    for (; j < e; ++j) { float4 c0 = ts[j]; PROC(c0); } }

__device__ __forceinline__ int bkt_of(float x) {
    int b = (int)((x - XLO) * XINVBW);
    return min(max(b, 0), NB - 1);
}

// ---------------- 1: zero bucket counters
__global__ void zero_counts(int* cur_t, int* cur_q) {
    int t = blockIdx.x * blockDim.x + threadIdx.x;
    if (t < NB) { cur_t[t] = 0; cur_q[t] = 0; }
}

// ---------------- 2: histogram targets and queries by x
__global__ void histo(const float* __restrict__ tc, const float* __restrict__ tf,
                      int* cur_t, int* cur_q, int M, int N) {
    int i = blockIdx.x * blockDim.x + threadIdx.x;
    if (i < M) atomicAdd(&cur_t[bkt_of(tc[3 * i])], 1);
    if (i < N) atomicAdd(&cur_q[bkt_of(tf[6 * i])], 1);
}

// ---------------- 3: exclusive prefix scan of both histograms (one block)
__global__ __launch_bounds__(NB) void scan_counts(int* cur_t, int* cur_q,
                                                  int* start_t, int* start_q) {
    __shared__ int a[NB], b[NB];
    int t = threadIdx.x;
    int ct = cur_t[t], cq = cur_q[t];
    a[t] = ct; b[t] = cq;
    __syncthreads();
    for (int off = 1; off < NB; off <<= 1) {
        int av = a[t], bv = b[t];
        int au = (t >= off) ? a[t - off] : 0;
        int bu = (t >= off) ? b[t - off] : 0;
        __syncthreads();
        a[t] = av + au; b[t] = bv + bu;
        __syncthreads();
    }
    int et = a[t] - ct, eq = b[t] - cq;       // exclusive
    start_t[t] = et; start_q[t] = eq;
    cur_t[t] = et;  cur_q[t] = eq;            // scatter cursors
    if (t == NB - 1) { start_t[NB] = a[t]; start_q[NB] = b[t]; }
}

// ---------------- 4: scatter into x-bucket-sorted arrays
__global__ void scatter(const float* __restrict__ tc, const float* __restrict__ tf,
                        int* cur_t, int* cur_q,
                        float4* __restrict__ ts, float4* __restrict__ qs,
                        int* __restrict__ perm, int M, int N) {
    int i = blockIdx.x * blockDim.x + threadIdx.x;
    if (i < M) {
        float x = tc[3 * i], y = tc[3 * i + 1], z = tc[3 * i + 2];
        int p = atomicAdd(&cur_t[bkt_of(x)], 1);
        ts[p] = make_float4(-2.0f * x, -2.0f * y, -2.0f * z, x * x + y * y + z * z);
    }
    if (i < N) {
        float x = tf[6 * i], y = tf[6 * i + 1], z = tf[6 * i + 2];
        int p = atomicAdd(&cur_q[bkt_of(x)], 1);
        qs[p] = make_float4(x, y, z, x * x + y * y + z * z);
        perm[p] = i;
    }
}

// ---------------- 5: per-query expanding-ring scan over x-buckets.
// Exact: a skipped ring has min|dx| with dx^2 > b7 (current 8th-best d^2);
// d^2 >= dx^2 for every target there, and b7 only decreases -> latch is safe.
__global__ __launch_bounds__(64) void knn_scan(
    const float4* __restrict__ qs, const float4* __restrict__ ts,
    const int* __restrict__ start_t, const int* __restrict__ perm,
    float* __restrict__ out, int NQ) {
    int i = blockIdx.x * 64 + threadIdx.x;
    if (i >= NQ) return;
    float4 Q = qs[i];
    float qx = Q.x, qy = Q.y, qz = Q.z, q2 = Q.w;
    float b0 = BIGF, b1 = BIGF, b2 = BIGF, b3 = BIGF;
    float b4 = BIGF, b5 = BIGF, b6 = BIGF, b7 = BIGF;

    int qb = bkt_of(qx);
    SCANB(qb);
    int lb = qb;          // next left bucket to scan is lb-1
    int rb = qb + 1;      // next right bucket to scan is rb
    bool goL = (lb > 0), goR = (rb < NB);
    while (goL || goR) {
        if (goL) {
            float dx = fmaxf(qx - (XLO + lb * XBW), 0.0f);   // right edge of bucket lb-1
            if (dx * dx > b7 + 1e-3f) goL = false;
            else { --lb; SCANB(lb); goL = (lb > 0); }
        }
        if (goR) {
            float dx = fmaxf((XLO + rb * XBW) - qx, 0.0f);   // left edge of bucket rb
            if (dx * dx > b7 + 1e-3f) goR = false;
            else { SCANB(rb); ++rb; goR = (rb < NB); }
        }
    }

    float d0 = sqrtf(fmaxf(b0, 0.0f));
    float d1 = sqrtf(fmaxf(b1, 0.0f));
    float d2_ = sqrtf(fmaxf(b2, 0.0f));
    float d3 = sqrtf(fmaxf(b3, 0.0f));
    float d4 = sqrtf(fmaxf(b4, 0.0f));
    float d5 = sqrtf(fmaxf(b5, 0.0f));
    float d6 = sqrtf(fmaxf(b6, 0.0f));
    float d7 = sqrtf(fmaxf(b7, 0.0f));
    float m = (d0 > OCC_R) ? 1.0f : 0.0f;
    float* o = out + (size_t)perm[i] * KNB;
    ((float4*)o)[0] = make_float4(d0 * m, d1 * m, d2_ * m, d3 * m);
    ((float4*)o)[1] = make_float4(d4 * m, d5 * m, d6 * m, d7 * m);
}

extern "C" void kernel_launch(void* const* d_in, const int* in_sizes, int n_in,
                              void* d_out, int out_size, void* d_ws, size_t ws_size,
                              hipStream_t stream) {
    const float* tf = (const float*)d_in[0];   // to_filter (N x 6)
    const float* tc = (const float*)d_in[1];   // target_coords (M x 3)
    int N = in_sizes[0] / 6;                   // 32768
    int M = in_sizes[1] / 3;                   // 16384
    float* outp = (float*)d_out;

    char* w = (char*)d_ws;
    float4* ts = (float4*)w;                 w += ((size_t)M * 16 + 255) & ~(size_t)255;
    float4* qs = (float4*)w;                 w += ((size_t)N * 16 + 255) & ~(size_t)255;
    int* perm = (int*)w;                     w += ((size_t)N * 4 + 255) & ~(size_t)255;
    int* start_t = (int*)w;                  w += ((NB + 1) * 4 + 255) & ~(size_t)255;
    int* start_q = (int*)w;                  w += ((NB + 1) * 4 + 255) & ~(size_t)255;
    int* cur_t = (int*)w;                    w += (NB * 4 + 255) & ~(size_t)255;
    int* cur_q = (int*)w;

    zero_counts<<<(NB + 255) / 256, 256, 0, stream>>>(cur_t, cur_q);
    histo<<<(N + 255) / 256, 256, 0, stream>>>(tc, tf, cur_t, cur_q, M, N);
    scan_counts<<<1, NB, 0, stream>>>(cur_t, cur_q, start_t, start_q);
    scatter<<<(N + 255) / 256, 256, 0, stream>>>(tc, tf, cur_t, cur_q, ts, qs, perm, M, N);
    knn_scan<<<(N + 63) / 64, 64, 0, stream>>>(qs, ts, start_t, perm, outp, N);
}

// Round 12
// 236.101 us; speedup vs baseline: 3.6358x; 3.6358x over previous
//
#include <hip/hip_runtime.h>

#define KNB 8
#define OCC_R 0.25f
#define BIGF 1e30f
#define NB 256
#define XLO -6.0f
#define XBW (12.0f / NB)
#define XINVBW (NB / 12.0f)
#define G 16

__device__ __forceinline__ float med3f(float a, float b, float c) {
#if defined(__has_builtin) && __has_builtin(__builtin_amdgcn_fmed3f)
    return __builtin_amdgcn_fmed3f(a, b, c);   // single v_med3_f32
#else
    return fmaxf(fminf(a, b), fminf(fmaxf(a, b), c));
#endif
}

// Unconditional parallel insert of x into sorted-ascending b0..b7 (drops old b7).
#define INS8(val) { float x = (val);          \
    b7 = med3f(b6, b7, x);                    \
    b6 = med3f(b5, b6, x);                    \
    b5 = med3f(b4, b5, x);                    \
    b4 = med3f(b3, b4, x);                    \
    b3 = med3f(b2, b3, x);                    \
    b2 = med3f(b1, b2, x);                    \
    b1 = med3f(b0, b1, x);                    \
    b0 = fminf(b0, x); }

#define PROC(c) { float d2 = q2 + (c).w;      \
    d2 = fmaf((c).x, qx, d2);                 \
    d2 = fmaf((c).y, qy, d2);                 \
    d2 = fmaf((c).z, qz, d2);                 \
    INS8(d2); }

// group-cooperative bucket scan: lane gl handles start+gl, start+gl+G, ...
// (coalesced 256B per group), 2x batched so loads pipeline.
#define SCANB(bb) { int j = start_t[bb] + gl, e = start_t[(bb) + 1];     \
    for (; j + G < e; j += 2 * G) {                                      \
        float4 c0 = ts[j]; float4 c1 = ts[j + G];                        \
        PROC(c0); PROC(c1);                                              \
    }                                                                    \
    if (j < e) { float4 c0 = ts[j]; PROC(c0); } }

__device__ __forceinline__ int bkt_of(float x) {
    int b = (int)((x - XLO) * XINVBW);
    return min(max(b, 0), NB - 1);
}

// ---------------- 1: zero bucket counters
__global__ void zero_counts(int* cur_t, int* cur_q) {
    int t = blockIdx.x * blockDim.x + threadIdx.x;
    if (t < NB) { cur_t[t] = 0; cur_q[t] = 0; }
}

// ---------------- 2: histogram targets and queries by x
__global__ void histo(const float* __restrict__ tc, const float* __restrict__ tf,
                      int* cur_t, int* cur_q, int M, int N) {
    int i = blockIdx.x * blockDim.x + threadIdx.x;
    if (i < M) atomicAdd(&cur_t[bkt_of(tc[3 * i])], 1);
    if (i < N) atomicAdd(&cur_q[bkt_of(tf[6 * i])], 1);
}

// ---------------- 3: exclusive prefix scan of both histograms (one block)
__global__ __launch_bounds__(NB) void scan_counts(int* cur_t, int* cur_q,
                                                  int* start_t, int* start_q) {
    __shared__ int a[NB], b[NB];
    int t = threadIdx.x;
    int ct = cur_t[t], cq = cur_q[t];
    a[t] = ct; b[t] = cq;
    __syncthreads();
    for (int off = 1; off < NB; off <<= 1) {
        int av = a[t], bv = b[t];
        int au = (t >= off) ? a[t - off] : 0;
        int bu = (t >= off) ? b[t - off] : 0;
        __syncthreads();
        a[t] = av + au; b[t] = bv + bu;
        __syncthreads();
    }
    int et = a[t] - ct, eq = b[t] - cq;       // exclusive
    start_t[t] = et; start_q[t] = eq;
    cur_t[t] = et;  cur_q[t] = eq;            // scatter cursors
    if (t == NB - 1) { start_t[NB] = a[t]; start_q[NB] = b[t]; }
}

// ---------------- 4: scatter into x-bucket-sorted arrays
__global__ void scatter(const float* __restrict__ tc, const float* __restrict__ tf,
                        int* cur_t, int* cur_q,
                        float4* __restrict__ ts, float4* __restrict__ qs,
                        int* __restrict__ perm, int M, int N) {
    int i = blockIdx.x * blockDim.x + threadIdx.x;
    if (i < M) {
        float x = tc[3 * i], y = tc[3 * i + 1], z = tc[3 * i + 2];
        int p = atomicAdd(&cur_t[bkt_of(x)], 1);
        ts[p] = make_float4(-2.0f * x, -2.0f * y, -2.0f * z, x * x + y * y + z * z);
    }
    if (i < N) {
        float x = tf[6 * i], y = tf[6 * i + 1], z = tf[6 * i + 2];
        int p = atomicAdd(&cur_q[bkt_of(x)], 1);
        qs[p] = make_float4(x, y, z, x * x + y * y + z * z);
        perm[p] = i;
    }
}

// ---------------- 5: G=16 lanes cooperate per query; expanding-ring over x-buckets.
// Prune bound ub = min over group's per-lane b7: each lane's top-8 is a subset of
// the union, so union-8th <= every lane's b7 -> ub is a safe (conservative) bound.
// Control is group-uniform (ub, qx shared) -> no intra-group divergence.
__global__ __launch_bounds__(256) void knn_scan(
    const float4* __restrict__ qs, const float4* __restrict__ ts,
    const int* __restrict__ start_t, const int* __restrict__ perm,
    float* __restrict__ out, int NQ) {
    int tid = blockIdx.x * 256 + threadIdx.x;
    int gid = tid / G;                 // query (sorted order)
    int gl = tid & (G - 1);            // lane within group
    if (gid >= NQ) return;

    float4 Q = qs[gid];
    float qx = Q.x, qy = Q.y, qz = Q.z, q2 = Q.w;
    float b0 = BIGF, b1 = BIGF, b2 = BIGF, b3 = BIGF;
    float b4 = BIGF, b5 = BIGF, b6 = BIGF, b7 = BIGF;

    int qb = bkt_of(qx);
    SCANB(qb);
    int lb = qb;          // next left bucket to scan is lb-1
    int rb = qb + 1;      // next right bucket to scan is rb
    bool goL = (lb > 0), goR = (rb < NB);
    while (goL || goR) {
        // group-min of b7 (safe upper bound of the union's 8th-best)
        float ub = b7;
        ub = fminf(ub, __shfl_xor(ub, 1));
        ub = fminf(ub, __shfl_xor(ub, 2));
        ub = fminf(ub, __shfl_xor(ub, 4));
        ub = fminf(ub, __shfl_xor(ub, 8));
        if (goL) {
            float dx = fmaxf(qx - (XLO + lb * XBW), 0.0f);   // right edge of bucket lb-1
            if (dx * dx > ub + 1e-3f) goL = false;
            else { --lb; SCANB(lb); goL = (lb > 0); }
        }
        if (goR) {
            float dx = fmaxf((XLO + rb * XBW) - qx, 0.0f);   // left edge of bucket rb
            if (dx * dx > ub + 1e-3f) goR = false;
            else { SCANB(rb); ++rb; goR = (rb < NB); }
        }
    }

    // butterfly merge of the G sorted-8 lists (all lanes end with union top-8)
    #pragma unroll
    for (int s = 1; s < G; s <<= 1) {
        float n0 = __shfl_xor(b0, s), n1 = __shfl_xor(b1, s);
        float n2 = __shfl_xor(b2, s), n3 = __shfl_xor(b3, s);
        float n4 = __shfl_xor(b4, s), n5 = __shfl_xor(b5, s);
        float n6 = __shfl_xor(b6, s), n7 = __shfl_xor(b7, s);
        INS8(n0); INS8(n1); INS8(n2); INS8(n3);
        INS8(n4); INS8(n5); INS8(n6); INS8(n7);
    }

    if (gl == 0) {
        float d0 = sqrtf(fmaxf(b0, 0.0f));
        float d1 = sqrtf(fmaxf(b1, 0.0f));
        float d2_ = sqrtf(fmaxf(b2, 0.0f));
        float d3 = sqrtf(fmaxf(b3, 0.0f));
        float d4 = sqrtf(fmaxf(b4, 0.0f));
        float d5 = sqrtf(fmaxf(b5, 0.0f));
        float d6 = sqrtf(fmaxf(b6, 0.0f));
        float d7 = sqrtf(fmaxf(b7, 0.0f));
        float m = (d0 > OCC_R) ? 1.0f : 0.0f;
        float* o = out + (size_t)perm[gid] * KNB;
        ((float4*)o)[0] = make_float4(d0 * m, d1 * m, d2_ * m, d3 * m);
        ((float4*)o)[1] = make_float4(d4 * m, d5 * m, d6 * m, d7 * m);
    }
}

extern "C" void kernel_launch(void* const* d_in, const int* in_sizes, int n_in,
                              void* d_out, int out_size, void* d_ws, size_t ws_size,
                              hipStream_t stream) {
    const float* tf = (const float*)d_in[0];   // to_filter (N x 6)
    const float* tc = (const float*)d_in[1];   // target_coords (M x 3)
    int N = in_sizes[0] / 6;                   // 32768
    int M = in_sizes[1] / 3;                   // 16384
    float* outp = (float*)d_out;

    char* w = (char*)d_ws;
    float4* ts = (float4*)w;                 w += ((size_t)M * 16 + 255) & ~(size_t)255;
    float4* qs = (float4*)w;                 w += ((size_t)N * 16 + 255) & ~(size_t)255;
    int* perm = (int*)w;                     w += ((size_t)N * 4 + 255) & ~(size_t)255;
    int* start_t = (int*)w;                  w += ((NB + 1) * 4 + 255) & ~(size_t)255;
    int* start_q = (int*)w;                  w += ((NB + 1) * 4 + 255) & ~(size_t)255;
    int* cur_t = (int*)w;                    w += (NB * 4 + 255) & ~(size_t)255;
    int* cur_q = (int*)w;

    zero_counts<<<(NB + 255) / 256, 256, 0, stream>>>(cur_t, cur_q);
    histo<<<(N + 255) / 256, 256, 0, stream>>>(tc, tf, cur_t, cur_q, M, N);
    scan_counts<<<1, NB, 0, stream>>>(cur_t, cur_q, start_t, start_q);
    scatter<<<(N + 255) / 256, 256, 0, stream>>>(tc, tf, cur_t, cur_q, ts, qs, perm, M, N);
    // N*G threads: G=16 lanes per query -> 2048 blocks = 8 blocks/CU
    knn_scan<<<((size_t)N * G + 255) / 256, 256, 0, stream>>>(qs, ts, start_t, perm, outp, N);
}

// Round 13
// 233.539 us; speedup vs baseline: 3.6757x; 1.0110x over previous
//
#include <hip/hip_runtime.h>

#define KNB 8
#define OCC_R 0.25f
#define BIGF 1e30f
#define NB 256
#define XLO -6.0f
#define XBW (12.0f / NB)
#define XINVBW (NB / 12.0f)
#define G 16

__device__ __forceinline__ float med3f(float a, float b, float c) {
#if defined(__has_builtin) && __has_builtin(__builtin_amdgcn_fmed3f)
    return __builtin_amdgcn_fmed3f(a, b, c);   // single v_med3_f32
#else
    return fmaxf(fminf(a, b), fminf(fmaxf(a, b), c));
#endif
}

// Unconditional parallel insert of x into sorted-ascending b0..b7 (drops old b7).
#define INS8(val) { float x = (val);          \
    b7 = med3f(b6, b7, x);                    \
    b6 = med3f(b5, b6, x);                    \
    b5 = med3f(b4, b5, x);                    \
    b4 = med3f(b3, b4, x);                    \
    b3 = med3f(b2, b3, x);                    \
    b2 = med3f(b1, b2, x);                    \
    b1 = med3f(b0, b1, x);                    \
    b0 = fminf(b0, x); }

#define PROC(c) { float d2 = q2 + (c).w;      \
    d2 = fmaf((c).x, qx, d2);                 \
    d2 = fmaf((c).y, qy, d2);                 \
    d2 = fmaf((c).z, qz, d2);                 \
    INS8(d2); }

// group-cooperative bucket scan: lane gl handles start+gl, start+gl+G, ...
// (coalesced 256B per group), 2x batched so loads pipeline.
#define SCANB(bb) { int j = start_t[bb] + gl, e = start_t[(bb) + 1];     \
    for (; j + G < e; j += 2 * G) {                                      \
        float4 c0 = ts[j]; float4 c1 = ts[j + G];                        \
        PROC(c0); PROC(c1);                                              \
    }                                                                    \
    if (j < e) { float4 c0 = ts[j]; PROC(c0); } }

__device__ __forceinline__ int bkt_of(float x) {
    int b = (int)((x - XLO) * XINVBW);
    return min(max(b, 0), NB - 1);
}

// ---------------- 1: histogram targets and queries by x
__global__ void histo(const float* __restrict__ tc, const float* __restrict__ tf,
                      int* cur_t, int* cur_q, int M, int N) {
    int i = blockIdx.x * blockDim.x + threadIdx.x;
    if (i < M) atomicAdd(&cur_t[bkt_of(tc[3 * i])], 1);
    if (i < N) atomicAdd(&cur_q[bkt_of(tf[6 * i])], 1);
}

// ---------------- 2: exclusive prefix scan of both histograms (one block)
__global__ __launch_bounds__(NB) void scan_counts(int* cur_t, int* cur_q,
                                                  int* start_t, int* start_q) {
    __shared__ int a[NB], b[NB];
    int t = threadIdx.x;
    int ct = cur_t[t], cq = cur_q[t];
    a[t] = ct; b[t] = cq;
    __syncthreads();
    for (int off = 1; off < NB; off <<= 1) {
        int av = a[t], bv = b[t];
        int au = (t >= off) ? a[t - off] : 0;
        int bu = (t >= off) ? b[t - off] : 0;
        __syncthreads();
        a[t] = av + au; b[t] = bv + bu;
        __syncthreads();
    }
    int et = a[t] - ct, eq = b[t] - cq;       // exclusive
    start_t[t] = et; start_q[t] = eq;
    cur_t[t] = et;  cur_q[t] = eq;            // scatter cursors
    if (t == NB - 1) { start_t[NB] = a[t]; start_q[NB] = b[t]; }
}

// ---------------- 3: scatter into x-bucket-sorted arrays
__global__ void scatter(const float* __restrict__ tc, const float* __restrict__ tf,
                        int* cur_t, int* cur_q,
                        float4* __restrict__ ts, float4* __restrict__ qs,
                        int* __restrict__ perm, int M, int N) {
    int i = blockIdx.x * blockDim.x + threadIdx.x;
    if (i < M) {
        float x = tc[3 * i], y = tc[3 * i + 1], z = tc[3 * i + 2];
        int p = atomicAdd(&cur_t[bkt_of(x)], 1);
        ts[p] = make_float4(-2.0f * x, -2.0f * y, -2.0f * z, x * x + y * y + z * z);
    }
    if (i < N) {
        float x = tf[6 * i], y = tf[6 * i + 1], z = tf[6 * i + 2];
        int p = atomicAdd(&cur_q[bkt_of(x)], 1);
        qs[p] = make_float4(x, y, z, x * x + y * y + z * z);
        perm[p] = i;
    }
}

// ---------------- 4: G=16 lanes cooperate per query; expanding-ring over x-buckets.
// Prune bound ub = min( min-lane(b7), max-lane(b0) ):
//  - lane's top-8 is a subset of the union -> union-8th <= every lane's b7.
//  - the 16 per-lane minima are 16 DISTINCT candidates -> union-8th <= their max.
// The second term is finite after only 16 candidates (vs 128 for the first),
// which un-sticks sparse-tail queries (R12 straggler bug).
__global__ __launch_bounds__(256) void knn_scan(
    const float4* __restrict__ qs, const float4* __restrict__ ts,
    const int* __restrict__ start_t, const int* __restrict__ perm,
    float* __restrict__ out, int NQ) {
    int tid = blockIdx.x * 256 + threadIdx.x;
    int gid = tid / G;                 // query (sorted order)
    int gl = tid & (G - 1);            // lane within group
    if (gid >= NQ) return;

    float4 Q = qs[gid];
    float qx = Q.x, qy = Q.y, qz = Q.z, q2 = Q.w;
    float b0 = BIGF, b1 = BIGF, b2 = BIGF, b3 = BIGF;
    float b4 = BIGF, b5 = BIGF, b6 = BIGF, b7 = BIGF;

    int qb = bkt_of(qx);
    SCANB(qb);
    int lb = qb;          // next left bucket to scan is lb-1
    int rb = qb + 1;      // next right bucket to scan is rb
    bool goL = (lb > 0), goR = (rb < NB);
    while (goL || goR) {
        // two independent 4-stage reductions (latencies overlap)
        float um = b7;     // min-lane b7
        float u0 = b0;     // max-lane b0
        um = fminf(um, __shfl_xor(um, 1));  u0 = fmaxf(u0, __shfl_xor(u0, 1));
        um = fminf(um, __shfl_xor(um, 2));  u0 = fmaxf(u0, __shfl_xor(u0, 2));
        um = fminf(um, __shfl_xor(um, 4));  u0 = fmaxf(u0, __shfl_xor(u0, 4));
        um = fminf(um, __shfl_xor(um, 8));  u0 = fmaxf(u0, __shfl_xor(u0, 8));
        float ub = fminf(um, u0);
        if (goL) {
            float dx = fmaxf(qx - (XLO + lb * XBW), 0.0f);   // right edge of bucket lb-1
            if (dx * dx > ub + 1e-3f) goL = false;
            else { --lb; SCANB(lb); goL = (lb > 0); }
        }
        if (goR) {
            float dx = fmaxf((XLO + rb * XBW) - qx, 0.0f);   // left edge of bucket rb
            if (dx * dx > ub + 1e-3f) goR = false;
            else { SCANB(rb); ++rb; goR = (rb < NB); }
        }
    }

    // butterfly merge of the G sorted-8 lists (all lanes end with union top-8)
    #pragma unroll
    for (int s = 1; s < G; s <<= 1) {
        float n0 = __shfl_xor(b0, s), n1 = __shfl_xor(b1, s);
        float n2 = __shfl_xor(b2, s), n3 = __shfl_xor(b3, s);
        float n4 = __shfl_xor(b4, s), n5 = __shfl_xor(b5, s);
        float n6 = __shfl_xor(b6, s), n7 = __shfl_xor(b7, s);
        INS8(n0); INS8(n1); INS8(n2); INS8(n3);
        INS8(n4); INS8(n5); INS8(n6); INS8(n7);
    }

    if (gl == 0) {
        float d0 = sqrtf(fmaxf(b0, 0.0f));
        float d1 = sqrtf(fmaxf(b1, 0.0f));
        float d2_ = sqrtf(fmaxf(b2, 0.0f));
        float d3 = sqrtf(fmaxf(b3, 0.0f));
        float d4 = sqrtf(fmaxf(b4, 0.0f));
        float d5 = sqrtf(fmaxf(b5, 0.0f));
        float d6 = sqrtf(fmaxf(b6, 0.0f));
        float d7 = sqrtf(fmaxf(b7, 0.0f));
        float m = (d0 > OCC_R) ? 1.0f : 0.0f;
        float* o = out + (size_t)perm[gid] * KNB;
        ((float4*)o)[0] = make_float4(d0 * m, d1 * m, d2_ * m, d3 * m);
        ((float4*)o)[1] = make_float4(d4 * m, d5 * m, d6 * m, d7 * m);
    }
}

extern "C" void kernel_launch(void* const* d_in, const int* in_sizes, int n_in,
                              void* d_out, int out_size, void* d_ws, size_t ws_size,
                              hipStream_t stream) {
    const float* tf = (const float*)d_in[0];   // to_filter (N x 6)
    const float* tc = (const float*)d_in[1];   // target_coords (M x 3)
    int N = in_sizes[0] / 6;                   // 32768
    int M = in_sizes[1] / 3;                   // 16384
    float* outp = (float*)d_out;

    char* w = (char*)d_ws;
    float4* ts = (float4*)w;                 w += ((size_t)M * 16 + 255) & ~(size_t)255;
    float4* qs = (float4*)w;                 w += ((size_t)N * 16 + 255) & ~(size_t)255;
    int* perm = (int*)w;                     w += ((size_t)N * 4 + 255) & ~(size_t)255;
    int* start_t = (int*)w;                  w += ((NB + 1) * 4 + 255) & ~(size_t)255;
    int* start_q = (int*)w;                  w += ((NB + 1) * 4 + 255) & ~(size_t)255;
    int* cur_t = (int*)w;                    // cur_t and cur_q adjacent: one memset
    int* cur_q = cur_t + NB;

    hipMemsetAsync(cur_t, 0, 2 * NB * sizeof(int), stream);
    histo<<<(N + 255) / 256, 256, 0, stream>>>(tc, tf, cur_t, cur_q, M, N);
    scan_counts<<<1, NB, 0, stream>>>(cur_t, cur_q, start_t, start_q);
    scatter<<<(N + 255) / 256, 256, 0, stream>>>(tc, tf, cur_t, cur_q, ts, qs, perm, M, N);
    // N*G threads: G=16 lanes per query -> 2048 blocks = 8 blocks/CU
    knn_scan<<<((size_t)N * G + 255) / 256, 256, 0, stream>>>(qs, ts, start_t, perm, outp, N);
}

// Round 14
// 210.986 us; speedup vs baseline: 4.0686x; 1.1069x over previous
//
#include <hip/hip_runtime.h>

#define KNB 8
#define OCC_R 0.25f
#define BIGF 1e30f
#define NB 128
#define XLO -6.0f
#define XBW (12.0f / NB)
#define XINVBW (NB / 12.0f)
#define G 64

__device__ __forceinline__ float med3f(float a, float b, float c) {
#if defined(__has_builtin) && __has_builtin(__builtin_amdgcn_fmed3f)
    return __builtin_amdgcn_fmed3f(a, b, c);   // single v_med3_f32
#else
    return fmaxf(fminf(a, b), fminf(fmaxf(a, b), c));
#endif
}

// Unconditional parallel insert of x into sorted-ascending b0..b7 (drops old b7).
#define INS8(val) { float x = (val);          \
    b7 = med3f(b6, b7, x);                    \
    b6 = med3f(b5, b6, x);                    \
    b5 = med3f(b4, b5, x);                    \
    b4 = med3f(b3, b4, x);                    \
    b3 = med3f(b2, b3, x);                    \
    b2 = med3f(b1, b2, x);                    \
    b1 = med3f(b0, b1, x);                    \
    b0 = fminf(b0, x); }

#define PROC(c) { float d2 = q2 + (c).w;      \
    d2 = fmaf((c).x, qx, d2);                 \
    d2 = fmaf((c).y, qy, d2);                 \
    d2 = fmaf((c).z, qz, d2);                 \
    INS8(d2); }

// wave-cooperative bucket scan: lane gl handles start+gl, start+gl+G, ...
// 4-deep load batching keeps 4 independent 16B loads in flight per lane.
#define SCANB(bb) { int j = start_t[bb] + gl, e = start_t[(bb) + 1];       \
    for (; j + 3 * G < e; j += 4 * G) {                                    \
        float4 c0 = ts[j];         float4 c1 = ts[j + G];                  \
        float4 c2 = ts[j + 2 * G]; float4 c3 = ts[j + 3 * G];              \
        PROC(c0); PROC(c1); PROC(c2); PROC(c3);                            \
    }                                                                      \
    for (; j < e; j += G) { float4 c0 = ts[j]; PROC(c0); } }

__device__ __forceinline__ int bkt_of(float x) {
    int b = (int)((x - XLO) * XINVBW);
    return min(max(b, 0), NB - 1);
}

// ---------------- 1: histogram targets and queries by x (LDS-local, few global atomics)
__global__ __launch_bounds__(256) void histo(const float* __restrict__ tc,
                                             const float* __restrict__ tf,
                                             int* cur_t, int* cur_q, int M, int N) {
    __shared__ int h_t[NB], h_q[NB];
    for (int t = threadIdx.x; t < NB; t += 256) { h_t[t] = 0; h_q[t] = 0; }
    __syncthreads();
    int stride = gridDim.x * 256;
    for (int i = blockIdx.x * 256 + threadIdx.x; i < N; i += stride) {
        if (i < M) atomicAdd(&h_t[bkt_of(tc[3 * i])], 1);
        atomicAdd(&h_q[bkt_of(tf[6 * i])], 1);
    }
    __syncthreads();
    for (int t = threadIdx.x; t < NB; t += 256) {
        if (h_t[t]) atomicAdd(&cur_t[t], h_t[t]);
        if (h_q[t]) atomicAdd(&cur_q[t], h_q[t]);
    }
}

// ---------------- 2: exclusive prefix scan of both histograms (one block)
__global__ __launch_bounds__(NB) void scan_counts(int* cur_t, int* cur_q,
                                                  int* start_t, int* start_q) {
    __shared__ int a[NB], b[NB];
    int t = threadIdx.x;
    int ct = cur_t[t], cq = cur_q[t];
    a[t] = ct; b[t] = cq;
    __syncthreads();
    for (int off = 1; off < NB; off <<= 1) {
        int av = a[t], bv = b[t];
        int au = (t >= off) ? a[t - off] : 0;
        int bu = (t >= off) ? b[t - off] : 0;
        __syncthreads();
        a[t] = av + au; b[t] = bv + bu;
        __syncthreads();
    }
    int et = a[t] - ct, eq = b[t] - cq;       // exclusive
    start_t[t] = et; start_q[t] = eq;
    cur_t[t] = et;  cur_q[t] = eq;            // scatter cursors
    if (t == NB - 1) { start_t[NB] = a[t]; start_q[NB] = b[t]; }
}

// ---------------- 3: scatter into x-bucket-sorted arrays
__global__ void scatter(const float* __restrict__ tc, const float* __restrict__ tf,
                        int* cur_t, int* cur_q,
                        float4* __restrict__ ts, float4* __restrict__ qs,
                        int* __restrict__ perm, int M, int N) {
    int i = blockIdx.x * blockDim.x + threadIdx.x;
    if (i < M) {
        float x = tc[3 * i], y = tc[3 * i + 1], z = tc[3 * i + 2];
        int p = atomicAdd(&cur_t[bkt_of(x)], 1);
        ts[p] = make_float4(-2.0f * x, -2.0f * y, -2.0f * z, x * x + y * y + z * z);
    }
    if (i < N) {
        float x = tf[6 * i], y = tf[6 * i + 1], z = tf[6 * i + 2];
        int p = atomicAdd(&cur_q[bkt_of(x)], 1);
        qs[p] = make_float4(x, y, z, x * x + y * y + z * z);
        perm[p] = i;
    }
}

// ---------------- 4: ONE WAVE per query; expanding-ring over x-buckets.
// Wave-uniform control (no intra-wave divergence); 8192 blocks give the
// scheduler a deep queue so center-heavy queries don't leave CUs idle.
// Prune bound ub = min( min-lane(b7), max-lane(b0) ) — both conservative.
__global__ __launch_bounds__(256) void knn_scan(
    const float4* __restrict__ qs, const float4* __restrict__ ts,
    const int* __restrict__ start_t, const int* __restrict__ perm,
    float* __restrict__ out, int NQ) {
    int tid = blockIdx.x * 256 + threadIdx.x;
    int gid = tid / G;                 // query (sorted order) — one wave each
    int gl = tid & (G - 1);            // lane
    if (gid >= NQ) return;

    float4 Q = qs[gid];
    float qx = Q.x, qy = Q.y, qz = Q.z, q2 = Q.w;
    float b0 = BIGF, b1 = BIGF, b2 = BIGF, b3 = BIGF;
    float b4 = BIGF, b5 = BIGF, b6 = BIGF, b7 = BIGF;

    int qb = bkt_of(qx);
    SCANB(qb);
    int lb = qb;          // next left bucket to scan is lb-1
    int rb = qb + 1;      // next right bucket to scan is rb
    bool goL = (lb > 0), goR = (rb < NB);
    while (goL || goR) {
        // 6-stage wave reductions; two independent chains overlap
        float um = b7;     // min-lane b7
        float u0 = b0;     // max-lane b0
        #pragma unroll
        for (int s = 1; s < G; s <<= 1) {
            um = fminf(um, __shfl_xor(um, s));
            u0 = fmaxf(u0, __shfl_xor(u0, s));
        }
        float ub = fminf(um, u0);
        if (goL) {
            float dx = fmaxf(qx - (XLO + lb * XBW), 0.0f);   // right edge of bucket lb-1
            if (dx * dx > ub + 1e-3f) goL = false;
            else { --lb; SCANB(lb); goL = (lb > 0); }
        }
        if (goR) {
            float dx = fmaxf((XLO + rb * XBW) - qx, 0.0f);   // left edge of bucket rb
            if (dx * dx > ub + 1e-3f) goR = false;
            else { SCANB(rb); ++rb; goR = (rb < NB); }
        }
    }

    // butterfly merge of the 64 sorted-8 lists (all lanes end with union top-8)
    #pragma unroll
    for (int s = 1; s < G; s <<= 1) {
        float n0 = __shfl_xor(b0, s), n1 = __shfl_xor(b1, s);
        float n2 = __shfl_xor(b2, s), n3 = __shfl_xor(b3, s);
        float n4 = __shfl_xor(b4, s), n5 = __shfl_xor(b5, s);
        float n6 = __shfl_xor(b6, s), n7 = __shfl_xor(b7, s);
        INS8(n0); INS8(n1); INS8(n2); INS8(n3);
        INS8(n4); INS8(n5); INS8(n6); INS8(n7);
    }

    if (gl == 0) {
        float d0 = sqrtf(fmaxf(b0, 0.0f));
        float d1 = sqrtf(fmaxf(b1, 0.0f));
        float d2_ = sqrtf(fmaxf(b2, 0.0f));
        float d3 = sqrtf(fmaxf(b3, 0.0f));
        float d4 = sqrtf(fmaxf(b4, 0.0f));
        float d5 = sqrtf(fmaxf(b5, 0.0f));
        float d6 = sqrtf(fmaxf(b6, 0.0f));
        float d7 = sqrtf(fmaxf(b7, 0.0f));
        float m = (d0 > OCC_R) ? 1.0f : 0.0f;
        float* o = out + (size_t)perm[gid] * KNB;
        ((float4*)o)[0] = make_float4(d0 * m, d1 * m, d2_ * m, d3 * m);
        ((float4*)o)[1] = make_float4(d4 * m, d5 * m, d6 * m, d7 * m);
    }
}

extern "C" void kernel_launch(void* const* d_in, const int* in_sizes, int n_in,
                              void* d_out, int out_size, void* d_ws, size_t ws_size,
                              hipStream_t stream) {
    const float* tf = (const float*)d_in[0];   // to_filter (N x 6)
    const float* tc = (const float*)d_in[1];   // target_coords (M x 3)
    int N = in_sizes[0] / 6;                   // 32768
    int M = in_sizes[1] / 3;                   // 16384
    float* outp = (float*)d_out;

    char* w = (char*)d_ws;
    float4* ts = (float4*)w;                 w += ((size_t)M * 16 + 255) & ~(size_t)255;
    float4* qs = (float4*)w;                 w += ((size_t)N * 16 + 255) & ~(size_t)255;
    int* perm = (int*)w;                     w += ((size_t)N * 4 + 255) & ~(size_t)255;
    int* start_t = (int*)w;                  w += ((NB + 1) * 4 + 255) & ~(size_t)255;
    int* start_q = (int*)w;                  w += ((NB + 1) * 4 + 255) & ~(size_t)255;
    int* cur_t = (int*)w;                    // cur_t and cur_q adjacent: one memset
    int* cur_q = cur_t + NB;

    hipMemsetAsync(cur_t, 0, 2 * NB * sizeof(int), stream);
    histo<<<64, 256, 0, stream>>>(tc, tf, cur_t, cur_q, M, N);
    scan_counts<<<1, NB, 0, stream>>>(cur_t, cur_q, start_t, start_q);
    scatter<<<(N + 255) / 256, 256, 0, stream>>>(tc, tf, cur_t, cur_q, ts, qs, perm, M, N);
    // one 64-lane wave per query: N*G threads -> 8192 blocks (deep dynamic queue)
    knn_scan<<<((size_t)N * G + 255) / 256, 256, 0, stream>>>(qs, ts, start_t, perm, outp, N);
}